// Round 1
// baseline (942.606 us; speedup 1.0000x reference)
//
#include <hip/hip_runtime.h>
#include <hip/hip_bf16.h>
#include <cmath>

// Problem constants: B=1, S=2048, D=1024, H=16, dh=64
constexpr int Sdim = 2048;
constexpr int Ddim = 1024;
constexpr int Hn   = 16;
constexpr int DHd  = 64;
constexpr float NEGV = -1e18f;

// ---------------------------------------------------------------------------
// Generic C = (A @ B^T + bias) * scale
// A: (M x K) row-major, row stride K
// B: (N x K) row-major, row stride K  (so we dot rows of A with rows of B)
// C: (M x N) row-major, row stride N
// 64x64 block tile, 256 threads, each thread 4x4 outputs, K-tile = 16.
// ---------------------------------------------------------------------------
__global__ __launch_bounds__(256) void gemm_abt(
    const float* __restrict__ A, const float* __restrict__ B,
    const float* __restrict__ bias, float* __restrict__ C,
    int N, int K, float scale)
{
    int m0 = blockIdx.y * 64;
    int n0 = blockIdx.x * 64;
    __shared__ float As[16][64];
    __shared__ float Bs[16][64];
    int tid = threadIdx.x;
    int tx = tid & 15, ty = tid >> 4;
    int r = tid >> 2;            // 0..63
    int c = (tid & 3) << 2;      // 0,4,8,12

    float acc[4][4] = {};

    for (int k0 = 0; k0 < K; k0 += 16) {
        float4 av = *(const float4*)(A + (size_t)(m0 + r) * K + k0 + c);
        float4 bv = *(const float4*)(B + (size_t)(n0 + r) * K + k0 + c);
        __syncthreads();
        As[c + 0][r] = av.x; As[c + 1][r] = av.y; As[c + 2][r] = av.z; As[c + 3][r] = av.w;
        Bs[c + 0][r] = bv.x; Bs[c + 1][r] = bv.y; Bs[c + 2][r] = bv.z; Bs[c + 3][r] = bv.w;
        __syncthreads();
#pragma unroll
        for (int t = 0; t < 16; t++) {
            float4 a = *(const float4*)&As[t][ty << 2];
            float4 b = *(const float4*)&Bs[t][tx << 2];
            float aa[4] = {a.x, a.y, a.z, a.w};
            float bb[4] = {b.x, b.y, b.z, b.w};
#pragma unroll
            for (int i = 0; i < 4; i++)
#pragma unroll
                for (int j = 0; j < 4; j++)
                    acc[i][j] += aa[i] * bb[j];
        }
    }

#pragma unroll
    for (int i = 0; i < 4; i++) {
        int m = m0 + (ty << 2) + i;
        int n = n0 + (tx << 2);
        float4 o;
        o.x = (acc[i][0] + bias[n + 0]) * scale;
        o.y = (acc[i][1] + bias[n + 1]) * scale;
        o.z = (acc[i][2] + bias[n + 2]) * scale;
        o.w = (acc[i][3] + bias[n + 3]) * scale;
        *(float4*)(C + (size_t)m * N + n) = o;
    }
}

// ---------------------------------------------------------------------------
// scores[h,q,k] = sum_d Q[q, h*64+d] * K[k, h*64+d]   (Q pre-scaled)
// masked entries -> NEGV.  Written into the attn region of d_out.
// ---------------------------------------------------------------------------
__global__ __launch_bounds__(256) void scores_kernel(
    const float* __restrict__ Q, const float* __restrict__ Kp,
    const int* __restrict__ mask, float* __restrict__ attn)
{
    int h  = blockIdx.z;
    int m0 = blockIdx.y * 64;
    int n0 = blockIdx.x * 64;
    __shared__ float As[16][64];
    __shared__ float Bs[16][64];
    int tid = threadIdx.x;
    int tx = tid & 15, ty = tid >> 4;
    int r = tid >> 2;
    int c = (tid & 3) << 2;

    const float* Ab = Q + h * DHd;
    const float* Bb = Kp + h * DHd;

    float acc[4][4] = {};

    for (int k0 = 0; k0 < DHd; k0 += 16) {
        float4 av = *(const float4*)(Ab + (size_t)(m0 + r) * Ddim + k0 + c);
        float4 bv = *(const float4*)(Bb + (size_t)(n0 + r) * Ddim + k0 + c);
        __syncthreads();
        As[c + 0][r] = av.x; As[c + 1][r] = av.y; As[c + 2][r] = av.z; As[c + 3][r] = av.w;
        Bs[c + 0][r] = bv.x; Bs[c + 1][r] = bv.y; Bs[c + 2][r] = bv.z; Bs[c + 3][r] = bv.w;
        __syncthreads();
#pragma unroll
        for (int t = 0; t < 16; t++) {
            float4 a = *(const float4*)&As[t][ty << 2];
            float4 b = *(const float4*)&Bs[t][tx << 2];
            float aa[4] = {a.x, a.y, a.z, a.w};
            float bb[4] = {b.x, b.y, b.z, b.w};
#pragma unroll
            for (int i = 0; i < 4; i++)
#pragma unroll
                for (int j = 0; j < 4; j++)
                    acc[i][j] += aa[i] * bb[j];
        }
    }

#pragma unroll
    for (int i = 0; i < 4; i++) {
        int q = m0 + (ty << 2) + i;
        int n = n0 + (tx << 2);
        const int* mrow = mask + (size_t)q * Sdim + n;
        float4 o;
        o.x = mrow[0] ? NEGV : acc[i][0];
        o.y = mrow[1] ? NEGV : acc[i][1];
        o.z = mrow[2] ? NEGV : acc[i][2];
        o.w = mrow[3] ? NEGV : acc[i][3];
        *(float4*)(attn + (size_t)h * Sdim * Sdim + (size_t)q * Sdim + n) = o;
    }
}

// ---------------------------------------------------------------------------
// In-place row softmax over the last dim (S=2048). One block per row.
// ---------------------------------------------------------------------------
__global__ __launch_bounds__(256) void softmax_kernel(float* __restrict__ attn)
{
    size_t row = blockIdx.x;
    float* p = attn + row * (size_t)Sdim;
    int tid = threadIdx.x;

    float v[8];
    float m = -3.4e38f;
#pragma unroll
    for (int i = 0; i < 8; i++) {
        v[i] = p[tid + (i << 8)];
        m = fmaxf(m, v[i]);
    }

    __shared__ float red[256];
    red[tid] = m;
    __syncthreads();
    for (int off = 128; off > 0; off >>= 1) {
        if (tid < off) red[tid] = fmaxf(red[tid], red[tid + off]);
        __syncthreads();
    }
    m = red[0];
    __syncthreads();

    float s = 0.f;
#pragma unroll
    for (int i = 0; i < 8; i++) {
        v[i] = __expf(v[i] - m);
        s += v[i];
    }
    red[tid] = s;
    __syncthreads();
    for (int off = 128; off > 0; off >>= 1) {
        if (tid < off) red[tid] += red[tid + off];
        __syncthreads();
    }
    float inv = 1.0f / red[0];
#pragma unroll
    for (int i = 0; i < 8; i++)
        p[tid + (i << 8)] = v[i] * inv;
}

// ---------------------------------------------------------------------------
// ctx[q, h*64+d] = sum_k attn[h,q,k] * V[k, h*64+d]
// One block: 64 q-rows x full dh=64 cols for one head. K-loop over S.
// ---------------------------------------------------------------------------
__global__ __launch_bounds__(256) void pv_kernel(
    const float* __restrict__ P, const float* __restrict__ V,
    float* __restrict__ ctx)
{
    int h  = blockIdx.z;
    int m0 = blockIdx.y * 64;
    __shared__ float As[16][64];
    __shared__ float Bs[16][64];
    int tid = threadIdx.x;
    int tx = tid & 15, ty = tid >> 4;
    int r = tid >> 2;
    int c = (tid & 3) << 2;
    int vr = tid >> 4;            // 0..15 (V tile row)
    int vc = (tid & 15) << 2;     // 0..60 (V tile col)

    const float* Ph = P + (size_t)h * Sdim * Sdim;

    float acc[4][4] = {};

    for (int k0 = 0; k0 < Sdim; k0 += 16) {
        float4 av = *(const float4*)(Ph + (size_t)(m0 + r) * Sdim + k0 + c);
        float4 bv = *(const float4*)(V + (size_t)(k0 + vr) * Ddim + h * DHd + vc);
        __syncthreads();
        As[c + 0][r] = av.x; As[c + 1][r] = av.y; As[c + 2][r] = av.z; As[c + 3][r] = av.w;
        *(float4*)&Bs[vr][vc] = bv;
        __syncthreads();
#pragma unroll
        for (int t = 0; t < 16; t++) {
            float4 a = *(const float4*)&As[t][ty << 2];
            float4 b = *(const float4*)&Bs[t][tx << 2];
            float aa[4] = {a.x, a.y, a.z, a.w};
            float bb[4] = {b.x, b.y, b.z, b.w};
#pragma unroll
            for (int i = 0; i < 4; i++)
#pragma unroll
                for (int j = 0; j < 4; j++)
                    acc[i][j] += aa[i] * bb[j];
        }
    }

#pragma unroll
    for (int i = 0; i < 4; i++) {
        int m = m0 + (ty << 2) + i;
        float4 o;
        o.x = acc[i][0]; o.y = acc[i][1]; o.z = acc[i][2]; o.w = acc[i][3];
        *(float4*)(ctx + (size_t)m * Ddim + h * DHd + (tx << 2)) = o;
    }
}

extern "C" void kernel_launch(void* const* d_in, const int* in_sizes, int n_in,
                              void* d_out, int out_size, void* d_ws, size_t ws_size,
                              hipStream_t stream)
{
    const float* X    = (const float*)d_in[0];
    const int*   mask = (const int*)d_in[1];
    const float* Wq   = (const float*)d_in[2];
    const float* bq   = (const float*)d_in[3];
    const float* Wk   = (const float*)d_in[4];
    const float* bk   = (const float*)d_in[5];
    const float* Wv   = (const float*)d_in[6];
    const float* bv   = (const float*)d_in[7];
    const float* Wo   = (const float*)d_in[8];
    const float* bo   = (const float*)d_in[9];

    float* out  = (float*)d_out;
    float* attn = out + (size_t)Sdim * Ddim;   // second tuple element

    float* qws = (float*)d_ws;
    float* kws = qws + (size_t)Sdim * Ddim;
    float* vws = kws + (size_t)Sdim * Ddim;
    float* cws = vws + (size_t)Sdim * Ddim;

    dim3 blk(256);

    // Q/K/V projections (Q pre-scaled by 1/sqrt(dh) = 0.125)
    gemm_abt<<<dim3(Ddim / 64, Sdim / 64), blk, 0, stream>>>(X, Wq, bq, qws, Ddim, Ddim, 0.125f);
    gemm_abt<<<dim3(Ddim / 64, Sdim / 64), blk, 0, stream>>>(X, Wk, bk, kws, Ddim, Ddim, 1.0f);
    gemm_abt<<<dim3(Ddim / 64, Sdim / 64), blk, 0, stream>>>(X, Wv, bv, vws, Ddim, Ddim, 1.0f);

    // masked scores into attn region
    scores_kernel<<<dim3(Sdim / 64, Sdim / 64, Hn), blk, 0, stream>>>(qws, kws, mask, attn);

    // in-place softmax (H*S rows)
    softmax_kernel<<<dim3(Hn * Sdim), blk, 0, stream>>>(attn);

    // ctx = attn @ V (per head), interleaved back to (S, D)
    pv_kernel<<<dim3(1, Sdim / 64, Hn), blk, 0, stream>>>(attn, vws, cws);

    // output projection
    gemm_abt<<<dim3(Ddim / 64, Sdim / 64), blk, 0, stream>>>(cws, Wo, bo, out, Ddim, Ddim, 1.0f);
}

// Round 2
// 579.883 us; speedup vs baseline: 1.6255x; 1.6255x over previous
//
#include <hip/hip_runtime.h>
#include <hip/hip_bf16.h>

// B=1, S=2048, D=1024, H=16, dh=64
constexpr int S  = 2048;
constexpr int D  = 1024;
constexpr int H  = 16;
constexpr int DH = 64;

typedef __attribute__((ext_vector_type(8))) short short8;   // 8 bf16 = 4 VGPRs (MFMA A/B frag)
typedef __attribute__((ext_vector_type(4))) short short4v;
typedef __attribute__((ext_vector_type(4))) float floatx4;  // MFMA C/D frag

__device__ inline short f2b(float x) {  // fp32 -> bf16 RNE
    union { float f; unsigned u; } v; v.f = x;
    unsigned r = v.u + 0x7FFFu + ((v.u >> 16) & 1u);
    return (short)(r >> 16);
}

// ---------------------------------------------------------------------------
// fp32 -> bf16 elementwise (n multiple of 4)
// ---------------------------------------------------------------------------
__global__ __launch_bounds__(256) void cvt_kernel(const float* __restrict__ src,
                                                  short* __restrict__ dst, int n) {
    int base = (blockIdx.x * 256 + threadIdx.x) * 4;
    if (base >= n) return;
    float4 v = *(const float4*)(src + base);
    short4v o;
    o.x = f2b(v.x); o.y = f2b(v.y); o.z = f2b(v.z); o.w = f2b(v.w);
    *(short4v*)(dst + base) = o;
}

// ---------------------------------------------------------------------------
// Pack mask (int 0/1, SxS) into 64-bit words: bits[q*32 + w] bit j = mask[q][w*64+j]
// One wave produces one word via __ballot. Grid: S*S threads total.
// ---------------------------------------------------------------------------
__global__ __launch_bounds__(256) void maskpack_kernel(const int* __restrict__ mask,
                                                       unsigned long long* __restrict__ bits) {
    int gt   = blockIdx.x * 256 + threadIdx.x;
    int word = gt >> 6;
    int lane = gt & 63;
    int row  = word >> 5;       // 32 words per row
    int wcol = word & 31;
    int v = mask[(size_t)row * S + wcol * 64 + lane];
    unsigned long long b = __ballot(v != 0);
    if (lane == 0) bits[word] = b;
}

// ---------------------------------------------------------------------------
// C = A(MxK) . B(NxK)^T + bias, bf16 inputs, fp32 accumulate. 128x128 tile,
// 256 threads = 4 waves, each wave 64x64 via 4x4 MFMA 16x16x32 tiles, BK=32.
// mode: 0 = bf16 out row-major; 1 = bf16 out * 0.125 (Q); 2 = bf16 out
// transposed (o16[col*S + row], gives V as [h][dh][key]); 3 = fp32 out.
// ---------------------------------------------------------------------------
__global__ __launch_bounds__(256) void gemm_mfma(
    const short* __restrict__ A, const short* __restrict__ B,
    const float* __restrict__ bias,
    short* __restrict__ o16, float* __restrict__ o32, int mode)
{
    __shared__ short As[128 * 40];   // stride 40 bf16 = 80 B (2-way bank alias: free)
    __shared__ short Bs[128 * 40];
    int m0 = blockIdx.y * 128, n0 = blockIdx.x * 128;
    int tid = threadIdx.x;
    int w = tid >> 6, lane = tid & 63, quad = lane >> 4, l16 = lane & 15;
    int wm = w & 1, wn = w >> 1;

    floatx4 acc[4][4] = {};

    for (int k0 = 0; k0 < D; k0 += 32) {
        __syncthreads();
#pragma unroll
        for (int i = 0; i < 2; i++) {
            int c = tid + i * 256;          // 512 chunks of 8 bf16
            int r = c >> 2, cc = (c & 3) * 8;
            *(short8*)&As[r * 40 + cc] = *(const short8*)(A + (size_t)(m0 + r) * D + k0 + cc);
            *(short8*)&Bs[r * 40 + cc] = *(const short8*)(B + (size_t)(n0 + r) * D + k0 + cc);
        }
        __syncthreads();
        short8 af[4], bf[4];
#pragma unroll
        for (int mt = 0; mt < 4; mt++)
            af[mt] = *(short8*)&As[(wm * 64 + mt * 16 + l16) * 40 + quad * 8];
#pragma unroll
        for (int nt = 0; nt < 4; nt++)
            bf[nt] = *(short8*)&Bs[(wn * 64 + nt * 16 + l16) * 40 + quad * 8];
#pragma unroll
        for (int mt = 0; mt < 4; mt++)
#pragma unroll
            for (int nt = 0; nt < 4; nt++)
                acc[mt][nt] = __builtin_amdgcn_mfma_f32_16x16x32_bf16(af[mt], bf[nt], acc[mt][nt], 0, 0, 0);
    }

#pragma unroll
    for (int mt = 0; mt < 4; mt++)
#pragma unroll
        for (int nt = 0; nt < 4; nt++) {
            int col = n0 + wn * 64 + nt * 16 + l16;
            float bb = bias[col];
#pragma unroll
            for (int reg = 0; reg < 4; reg++) {
                int row = m0 + wm * 64 + mt * 16 + quad * 4 + reg;
                float v = acc[mt][nt][reg] + bb;
                if (mode == 0)      o16[(size_t)row * D + col] = f2b(v);
                else if (mode == 1) o16[(size_t)row * D + col] = f2b(v * 0.125f);
                else if (mode == 2) o16[(size_t)col * S + row] = f2b(v);
                else                o32[(size_t)row * D + col] = v;
            }
        }
}

// ---------------------------------------------------------------------------
// Fused attention: per block = one head x 64 Q rows. Two-pass exact softmax:
// pass 1: QK^T MFMA tiles + online row max / sumexp (scores not stored).
// pass 2: recompute scores, p = exp(s-m)/l -> write attn (fp32, the mandatory
// 268 MB), convert p to bf16 through LDS (C-layout -> A-layout), ctx += P.V
// via MFMA with V staged transposed [dh][key].
// ---------------------------------------------------------------------------
__global__ __launch_bounds__(256) void attn_kernel(
    const short* __restrict__ Qb,   // [S][D] bf16, pre-scaled by 1/8
    const short* __restrict__ Kb,   // [S][D] bf16
    const short* __restrict__ Vt,   // [H][DH][S] bf16 (transposed)
    const unsigned long long* __restrict__ bits,
    float* __restrict__ attn,       // [H][S][S] fp32
    short* __restrict__ ctxb)       // [S][D] bf16
{
    __shared__ short Qs[64 * 72];   // stride 72 bf16 = 144 B (2-way alias: free)
    __shared__ short Ks[64 * 72];
    __shared__ short Vs[64 * 72];   // Vs[dh][key]
    __shared__ short Ps[64 * 72];   // per-wave 16-row stripes
    int h = blockIdx.y, q0 = blockIdx.x * 64;
    int tid = threadIdx.x;
    int w = tid >> 6, lane = tid & 63, quad = lane >> 4, l16 = lane & 15;

    // stage Q tile (64 x 64)
#pragma unroll
    for (int i = 0; i < 2; i++) {
        int c = tid + i * 256;
        int r = c >> 3, cc = (c & 7) * 8;
        *(short8*)&Qs[r * 72 + cc] = *(const short8*)(Qb + (size_t)(q0 + r) * D + h * DH + cc);
    }
    __syncthreads();
    short8 aq0 = *(short8*)&Qs[(w * 16 + l16) * 72 + quad * 8];
    short8 aq1 = *(short8*)&Qs[(w * 16 + l16) * 72 + 32 + quad * 8];

    float m_r[4], l_r[4];
#pragma unroll
    for (int r = 0; r < 4; r++) { m_r[r] = -3.0e38f; l_r[r] = 0.0f; }

    // ---- pass 1: row max + sumexp ----
    for (int kt = 0; kt < 32; kt++) {
        int k0 = kt * 64;
        __syncthreads();
#pragma unroll
        for (int i = 0; i < 2; i++) {
            int c = tid + i * 256;
            int r = c >> 3, cc = (c & 7) * 8;
            *(short8*)&Ks[r * 72 + cc] = *(const short8*)(Kb + (size_t)(k0 + r) * D + h * DH + cc);
        }
        __syncthreads();
        floatx4 sc[4] = {};
#pragma unroll
        for (int nt = 0; nt < 4; nt++) {
            short8 b0 = *(short8*)&Ks[(nt * 16 + l16) * 72 + quad * 8];
            short8 b1 = *(short8*)&Ks[(nt * 16 + l16) * 72 + 32 + quad * 8];
            sc[nt] = __builtin_amdgcn_mfma_f32_16x16x32_bf16(aq0, b0, sc[nt], 0, 0, 0);
            sc[nt] = __builtin_amdgcn_mfma_f32_16x16x32_bf16(aq1, b1, sc[nt], 0, 0, 0);
        }
#pragma unroll
        for (int reg = 0; reg < 4; reg++) {
            int q = q0 + w * 16 + quad * 4 + reg;
            unsigned long long mw = bits[(size_t)q * 32 + kt];
            float sv[4], tmax = -3.0e38f;
#pragma unroll
            for (int nt = 0; nt < 4; nt++) {
                sv[nt] = ((mw >> (nt * 16 + l16)) & 1ull) ? -1e18f : sc[nt][reg];
                tmax = fmaxf(tmax, sv[nt]);
            }
#pragma unroll
            for (int d = 1; d < 16; d <<= 1) tmax = fmaxf(tmax, __shfl_xor(tmax, d));
            float mn = fmaxf(m_r[reg], tmax);
            float ssum = 0.0f;
#pragma unroll
            for (int nt = 0; nt < 4; nt++) ssum += __expf(sv[nt] - mn);
#pragma unroll
            for (int d = 1; d < 16; d <<= 1) ssum += __shfl_xor(ssum, d);
            l_r[reg] = l_r[reg] * __expf(m_r[reg] - mn) + ssum;
            m_r[reg] = mn;
        }
    }
    float inv_l[4];
#pragma unroll
    for (int r = 0; r < 4; r++) inv_l[r] = 1.0f / l_r[r];

    floatx4 cacc[4] = {};
    float* attnh = attn + (size_t)h * S * S;

    // ---- pass 2: write attn + accumulate ctx ----
    for (int kt = 0; kt < 32; kt++) {
        int k0 = kt * 64;
        __syncthreads();
#pragma unroll
        for (int i = 0; i < 2; i++) {
            int c = tid + i * 256;
            int r = c >> 3, cc = (c & 7) * 8;
            *(short8*)&Ks[r * 72 + cc] = *(const short8*)(Kb + (size_t)(k0 + r) * D + h * DH + cc);
            *(short8*)&Vs[r * 72 + cc] = *(const short8*)(Vt + (size_t)(h * DH + r) * S + k0 + cc);
        }
        __syncthreads();
        floatx4 sc[4] = {};
#pragma unroll
        for (int nt = 0; nt < 4; nt++) {
            short8 b0 = *(short8*)&Ks[(nt * 16 + l16) * 72 + quad * 8];
            short8 b1 = *(short8*)&Ks[(nt * 16 + l16) * 72 + 32 + quad * 8];
            sc[nt] = __builtin_amdgcn_mfma_f32_16x16x32_bf16(aq0, b0, sc[nt], 0, 0, 0);
            sc[nt] = __builtin_amdgcn_mfma_f32_16x16x32_bf16(aq1, b1, sc[nt], 0, 0, 0);
        }
#pragma unroll
        for (int reg = 0; reg < 4; reg++) {
            int q = q0 + w * 16 + quad * 4 + reg;
            unsigned long long mw = bits[(size_t)q * 32 + kt];
            float* arow = attnh + (size_t)q * S + k0;
#pragma unroll
            for (int nt = 0; nt < 4; nt++) {
                float sv = ((mw >> (nt * 16 + l16)) & 1ull) ? -1e18f : sc[nt][reg];
                float p = __expf(sv - m_r[reg]) * inv_l[reg];
                arow[nt * 16 + l16] = p;
                Ps[(w * 16 + quad * 4 + reg) * 72 + nt * 16 + l16] = f2b(p);
            }
        }
        // wave-local P stripe: LDS ordering within a wave needs no barrier
        short8 pa0 = *(short8*)&Ps[(w * 16 + l16) * 72 + quad * 8];
        short8 pa1 = *(short8*)&Ps[(w * 16 + l16) * 72 + 32 + quad * 8];
#pragma unroll
        for (int nt = 0; nt < 4; nt++) {
            short8 vb0 = *(short8*)&Vs[(nt * 16 + l16) * 72 + quad * 8];
            short8 vb1 = *(short8*)&Vs[(nt * 16 + l16) * 72 + 32 + quad * 8];
            cacc[nt] = __builtin_amdgcn_mfma_f32_16x16x32_bf16(pa0, vb0, cacc[nt], 0, 0, 0);
            cacc[nt] = __builtin_amdgcn_mfma_f32_16x16x32_bf16(pa1, vb1, cacc[nt], 0, 0, 0);
        }
    }

#pragma unroll
    for (int nt = 0; nt < 4; nt++)
#pragma unroll
        for (int reg = 0; reg < 4; reg++) {
            int q = q0 + w * 16 + quad * 4 + reg;
            ctxb[(size_t)q * D + h * DH + nt * 16 + l16] = f2b(cacc[nt][reg]);
        }
}

extern "C" void kernel_launch(void* const* d_in, const int* in_sizes, int n_in,
                              void* d_out, int out_size, void* d_ws, size_t ws_size,
                              hipStream_t stream)
{
    const float* X    = (const float*)d_in[0];
    const int*   mask = (const int*)d_in[1];
    const float* Wq   = (const float*)d_in[2];
    const float* bq   = (const float*)d_in[3];
    const float* Wk   = (const float*)d_in[4];
    const float* bk   = (const float*)d_in[5];
    const float* Wv   = (const float*)d_in[6];
    const float* bv   = (const float*)d_in[7];
    const float* Wo   = (const float*)d_in[8];
    const float* bo   = (const float*)d_in[9];

    float* out  = (float*)d_out;
    float* attn = out + (size_t)S * D;

    // workspace carve-up (bytes)
    char* ws = (char*)d_ws;
    short* Xb   = (short*)ws;                 ws += (size_t)S * D * 2;   // 4 MB
    short* Wqb  = (short*)ws;                 ws += (size_t)D * D * 2;   // 2 MB
    short* Wkb  = (short*)ws;                 ws += (size_t)D * D * 2;
    short* Wvb  = (short*)ws;                 ws += (size_t)D * D * 2;
    short* Wob  = (short*)ws;                 ws += (size_t)D * D * 2;
    short* Qb   = (short*)ws;                 ws += (size_t)S * D * 2;
    short* Kb   = (short*)ws;                 ws += (size_t)S * D * 2;
    short* Vt   = (short*)ws;                 ws += (size_t)S * D * 2;
    short* ctxb = (short*)ws;                 ws += (size_t)S * D * 2;
    unsigned long long* bits = (unsigned long long*)ws;                  // 512 KB

    dim3 blk(256);

    // prep: bf16 conversions + mask bit-pack
    cvt_kernel<<<dim3((S * D) / 1024), blk, 0, stream>>>(X, Xb, S * D);
    cvt_kernel<<<dim3((D * D) / 1024), blk, 0, stream>>>(Wq, Wqb, D * D);
    cvt_kernel<<<dim3((D * D) / 1024), blk, 0, stream>>>(Wk, Wkb, D * D);
    cvt_kernel<<<dim3((D * D) / 1024), blk, 0, stream>>>(Wv, Wvb, D * D);
    cvt_kernel<<<dim3((D * D) / 1024), blk, 0, stream>>>(Wo, Wob, D * D);
    maskpack_kernel<<<dim3((S * S) / 256), blk, 0, stream>>>(mask, bits);

    // projections (MFMA): Q scaled by 1/8; V written transposed [h][dh][key]
    gemm_mfma<<<dim3(D / 128, S / 128), blk, 0, stream>>>(Xb, Wqb, bq, Qb, nullptr, 1);
    gemm_mfma<<<dim3(D / 128, S / 128), blk, 0, stream>>>(Xb, Wkb, bk, Kb, nullptr, 0);
    gemm_mfma<<<dim3(D / 128, S / 128), blk, 0, stream>>>(Xb, Wvb, bv, Vt, nullptr, 2);

    // fused masked-softmax attention: writes attn (fp32) + ctx (bf16)
    attn_kernel<<<dim3(S / 64, H), blk, 0, stream>>>(Qb, Kb, Vt, bits, attn, ctxb);

    // output projection (fp32 out)
    gemm_mfma<<<dim3(D / 128, S / 128), blk, 0, stream>>>(ctxb, Wob, bo, nullptr, out, 3);
}

// Round 3
// 522.600 us; speedup vs baseline: 1.8037x; 1.1096x over previous
//
#include <hip/hip_runtime.h>
#include <hip/hip_bf16.h>

// B=1, S=2048, D=1024, H=16, dh=64
constexpr int S  = 2048;
constexpr int D  = 1024;
constexpr int H  = 16;
constexpr int DH = 64;

typedef __attribute__((ext_vector_type(8))) short short8;   // 8 bf16 (MFMA A/B frag)
typedef __attribute__((ext_vector_type(4))) short short4v;
typedef __attribute__((ext_vector_type(4))) float floatx4;  // MFMA C/D frag

__device__ inline short f2b(float x) {  // fp32 -> bf16 RNE
    union { float f; unsigned u; } v; v.f = x;
    unsigned r = v.u + 0x7FFFu + ((v.u >> 16) & 1u);
    return (short)(r >> 16);
}

// async 16B global -> LDS (per-lane global gather; LDS dest = lane-ordered)
__device__ inline void gl2lds16(const void* g, void* l) {
    __builtin_amdgcn_global_load_lds(
        (const __attribute__((address_space(1))) unsigned int*)g,
        (__attribute__((address_space(3))) unsigned int*)l, 16, 0, 0);
}

// ---------------------------------------------------------------------------
// fp32 -> bf16 elementwise
// ---------------------------------------------------------------------------
__global__ __launch_bounds__(256) void cvt_kernel(const float* __restrict__ src,
                                                  short* __restrict__ dst, int n) {
    int base = (blockIdx.x * 256 + threadIdx.x) * 4;
    if (base >= n) return;
    float4 v = *(const float4*)(src + base);
    short4v o;
    o.x = f2b(v.x); o.y = f2b(v.y); o.z = f2b(v.z); o.w = f2b(v.w);
    *(short4v*)(dst + base) = o;
}

// ---------------------------------------------------------------------------
// Pack mask into 64-bit words: bits[q*32 + w] bit j = mask[q][w*64+j]
// ---------------------------------------------------------------------------
__global__ __launch_bounds__(256) void maskpack_kernel(const int* __restrict__ mask,
                                                       unsigned long long* __restrict__ bits) {
    int gt   = blockIdx.x * 256 + threadIdx.x;
    int word = gt >> 6;
    int lane = gt & 63;
    int row  = word >> 5;
    int wcol = word & 31;
    int v = mask[(size_t)row * S + wcol * 64 + lane];
    unsigned long long b = __ballot(v != 0);
    if (lane == 0) bits[word] = b;
}

// ---------------------------------------------------------------------------
// C = A(MxK) . B(NxK)^T + bias. bf16 in, fp32 acc. 128x128 tile, BK=32,
// global_load_lds staging with XOR-swizzled groups (conflict-free reads).
// mode: 0 bf16 out; 1 bf16 out * 0.125 (Q); 2 bf16 out transposed (V^T); 3 fp32.
// ---------------------------------------------------------------------------
__global__ __launch_bounds__(256) void gemm_mfma(
    const short* __restrict__ A, const short* __restrict__ B,
    const float* __restrict__ bias,
    short* __restrict__ o16, float* __restrict__ o32, int mode)
{
    __shared__ short As[128 * 32];   // unpadded, XOR-swizzled by row
    __shared__ short Bs[128 * 32];
    int m0 = blockIdx.y * 128, n0 = blockIdx.x * 128;
    int tid = threadIdx.x;
    int w = tid >> 6, lane = tid & 63, quad = lane >> 4, l16 = lane & 15;
    int wm = w & 1, wn = w >> 1;

    // staging pointers: 512 chunks of 16B per operand, 2 per thread
    const short* ag[2]; const short* bg[2]; short* al[2]; short* bl[2];
#pragma unroll
    for (int i = 0; i < 2; i++) {
        int c = tid + i * 256;
        int r = c >> 2, g4 = c & 3, sg = g4 ^ (r & 3);
        ag[i] = A + (size_t)(m0 + r) * D + sg * 8;
        bg[i] = B + (size_t)(n0 + r) * D + sg * 8;
        al[i] = &As[c * 8];
        bl[i] = &Bs[c * 8];
    }

    floatx4 acc[4][4] = {};
    int gsw = quad ^ (l16 & 3);      // swizzled group for frag reads

    for (int k0 = 0; k0 < D; k0 += 32) {
        __syncthreads();
#pragma unroll
        for (int i = 0; i < 2; i++) {
            gl2lds16(ag[i] + k0, al[i]);
            gl2lds16(bg[i] + k0, bl[i]);
        }
        __syncthreads();
        short8 af[4], bf[4];
#pragma unroll
        for (int mt = 0; mt < 4; mt++)
            af[mt] = *(short8*)&As[(wm * 64 + mt * 16 + l16) * 32 + gsw * 8];
#pragma unroll
        for (int nt = 0; nt < 4; nt++)
            bf[nt] = *(short8*)&Bs[(wn * 64 + nt * 16 + l16) * 32 + gsw * 8];
#pragma unroll
        for (int mt = 0; mt < 4; mt++)
#pragma unroll
            for (int nt = 0; nt < 4; nt++)
                acc[mt][nt] = __builtin_amdgcn_mfma_f32_16x16x32_bf16(af[mt], bf[nt], acc[mt][nt], 0, 0, 0);
    }

#pragma unroll
    for (int mt = 0; mt < 4; mt++)
#pragma unroll
        for (int nt = 0; nt < 4; nt++) {
            int col = n0 + wn * 64 + nt * 16 + l16;
            float bb = bias[col];
#pragma unroll
            for (int reg = 0; reg < 4; reg++) {
                int row = m0 + wm * 64 + mt * 16 + quad * 4 + reg;
                float v = acc[mt][nt][reg] + bb;
                if (mode == 0)      o16[(size_t)row * D + col] = f2b(v);
                else if (mode == 1) o16[(size_t)row * D + col] = f2b(v * 0.125f);
                else if (mode == 2) o16[(size_t)col * S + row] = f2b(v);
                else                o32[(size_t)row * D + col] = v;
            }
        }
}

// ---------------------------------------------------------------------------
// Fused attention: block = one head x 64 Q rows, K-tile = 128, 16 iters/pass.
// Q frags live in registers. K/V staged via global_load_lds with XOR swizzle.
// Pass 1: online row max + sumexp. Pass 2: recompute scores, write normalized
// attn (fp32), P->bf16 via LDS, ctx += P.V (MFMA).
// ---------------------------------------------------------------------------
__global__ __launch_bounds__(256) void attn_kernel(
    const short* __restrict__ Qb,   // [S][D] bf16, pre-scaled
    const short* __restrict__ Kb,   // [S][D] bf16
    const short* __restrict__ Vt,   // [D][S] bf16 = per-head V^T [h*64+dh][key]
    const unsigned long long* __restrict__ bits,
    float* __restrict__ attn,       // [H][S][S] fp32
    short* __restrict__ ctxb)       // [S][D] bf16
{
    __shared__ short Ks[128 * 64];  // unpadded, swizzled (rows = keys)
    __shared__ short Vs[64 * 128];  // unpadded, swizzled (rows = dh)
    __shared__ short Ps[64 * 136];  // padded (also used to stage Q, stride 72)
    int h = blockIdx.y, q0 = blockIdx.x * 64;
    int tid = threadIdx.x;
    int w = tid >> 6, lane = tid & 63, quad = lane >> 4, l16 = lane & 15;

    // stage Q tile (64x64) into Ps (stride 72), grab frags into regs
#pragma unroll
    for (int i = 0; i < 2; i++) {
        int c = tid + i * 256;
        int r = c >> 3, cc = (c & 7) * 8;
        *(short8*)&Ps[r * 72 + cc] = *(const short8*)(Qb + (size_t)(q0 + r) * D + h * DH + cc);
    }
    __syncthreads();
    short8 aq0 = *(short8*)&Ps[(w * 16 + l16) * 72 + quad * 8];
    short8 aq1 = *(short8*)&Ps[(w * 16 + l16) * 72 + 32 + quad * 8];

    // K staging: 1024 chunks (128 rows x 8 groups), 4 per thread, XOR swizzle
    const short* kg[4]; short* kl[4];
#pragma unroll
    for (int i = 0; i < 4; i++) {
        int c = tid + i * 256;
        int r = c >> 3, c8 = c & 7, sg = c8 ^ (r & 7);
        kg[i] = Kb + (size_t)r * D + h * DH + sg * 8;
        kl[i] = &Ks[c * 8];
    }
    // V staging: 1024 chunks (64 rows x 16 groups), 4 per thread
    const short* vg[4]; short* vl[4];
#pragma unroll
    for (int i = 0; i < 4; i++) {
        int c = tid + i * 256;
        int r = c >> 4, c16 = c & 15, sg = c16 ^ (r & 15);
        vg[i] = Vt + (size_t)(h * DH + r) * S + sg * 8;
        vl[i] = &Vs[c * 8];
    }

    int g0 = quad ^ (l16 & 7);        // K frag groups (k 0..31)
    int g1 = (quad + 4) ^ (l16 & 7);  // K frag groups (k 32..63)

    float m_r[4], l_r[4];
#pragma unroll
    for (int r = 0; r < 4; r++) { m_r[r] = -3.0e38f; l_r[r] = 0.0f; }

    // ---- pass 1: row max + sumexp ----
    for (int kt = 0; kt < 16; kt++) {
        __syncthreads();
#pragma unroll
        for (int i = 0; i < 4; i++) gl2lds16(kg[i] + (size_t)kt * 128 * D, kl[i]);
        __syncthreads();
        floatx4 sc[8] = {};
#pragma unroll
        for (int nt = 0; nt < 8; nt++) {
            int row = nt * 16 + l16;
            short8 b0 = *(short8*)&Ks[row * 64 + g0 * 8];
            short8 b1 = *(short8*)&Ks[row * 64 + g1 * 8];
            sc[nt] = __builtin_amdgcn_mfma_f32_16x16x32_bf16(aq0, b0, sc[nt], 0, 0, 0);
            sc[nt] = __builtin_amdgcn_mfma_f32_16x16x32_bf16(aq1, b1, sc[nt], 0, 0, 0);
        }
#pragma unroll
        for (int reg = 0; reg < 4; reg++) {
            int q = q0 + w * 16 + quad * 4 + reg;
            const unsigned long long* bw = bits + (size_t)q * 32 + kt * 2;
            unsigned long long w0 = bw[0], w1 = bw[1];
            float sv[8], tmax = -3.0e38f;
#pragma unroll
            for (int nt = 0; nt < 4; nt++) {
                sv[nt] = ((w0 >> (nt * 16 + l16)) & 1ull) ? -1e18f : sc[nt][reg];
                tmax = fmaxf(tmax, sv[nt]);
            }
#pragma unroll
            for (int nt = 4; nt < 8; nt++) {
                sv[nt] = ((w1 >> ((nt - 4) * 16 + l16)) & 1ull) ? -1e18f : sc[nt][reg];
                tmax = fmaxf(tmax, sv[nt]);
            }
#pragma unroll
            for (int d = 1; d < 16; d <<= 1) tmax = fmaxf(tmax, __shfl_xor(tmax, d));
            float mn = fmaxf(m_r[reg], tmax);
            float ssum = 0.0f;
#pragma unroll
            for (int nt = 0; nt < 8; nt++) ssum += __expf(sv[nt] - mn);
#pragma unroll
            for (int d = 1; d < 16; d <<= 1) ssum += __shfl_xor(ssum, d);
            l_r[reg] = l_r[reg] * __expf(m_r[reg] - mn) + ssum;
            m_r[reg] = mn;
        }
    }
    float inv_l[4];
#pragma unroll
    for (int r = 0; r < 4; r++) inv_l[r] = 1.0f / l_r[r];

    floatx4 cacc[4] = {};
    float* attnh = attn + (size_t)h * S * S;

    // ---- pass 2: write attn + accumulate ctx ----
    for (int kt = 0; kt < 16; kt++) {
        int k0 = kt * 128;
        __syncthreads();
#pragma unroll
        for (int i = 0; i < 4; i++) {
            gl2lds16(kg[i] + (size_t)kt * 128 * D, kl[i]);
            gl2lds16(vg[i] + k0, vl[i]);
        }
        __syncthreads();
        floatx4 sc[8] = {};
#pragma unroll
        for (int nt = 0; nt < 8; nt++) {
            int row = nt * 16 + l16;
            short8 b0 = *(short8*)&Ks[row * 64 + g0 * 8];
            short8 b1 = *(short8*)&Ks[row * 64 + g1 * 8];
            sc[nt] = __builtin_amdgcn_mfma_f32_16x16x32_bf16(aq0, b0, sc[nt], 0, 0, 0);
            sc[nt] = __builtin_amdgcn_mfma_f32_16x16x32_bf16(aq1, b1, sc[nt], 0, 0, 0);
        }
#pragma unroll
        for (int reg = 0; reg < 4; reg++) {
            int q = q0 + w * 16 + quad * 4 + reg;
            const unsigned long long* bw = bits + (size_t)q * 32 + kt * 2;
            unsigned long long w0 = bw[0], w1 = bw[1];
            float* arow = attnh + (size_t)q * S + k0;
#pragma unroll
            for (int nt = 0; nt < 8; nt++) {
                unsigned long long msk = (nt < 4) ? (w0 >> (nt * 16 + l16))
                                                  : (w1 >> ((nt - 4) * 16 + l16));
                float svv = (msk & 1ull) ? -1e18f : sc[nt][reg];
                float p = __expf(svv - m_r[reg]) * inv_l[reg];
                arow[nt * 16 + l16] = p;
                Ps[(w * 16 + quad * 4 + reg) * 136 + nt * 16 + l16] = f2b(p);
            }
        }
        // PV: wave-local Ps stripe (same-wave LDS ordering; no barrier needed)
        short8 pa[4];
#pragma unroll
        for (int kc = 0; kc < 4; kc++)
            pa[kc] = *(short8*)&Ps[(w * 16 + l16) * 136 + kc * 32 + quad * 8];
#pragma unroll
        for (int nt = 0; nt < 4; nt++) {
            int d = nt * 16 + l16;
#pragma unroll
            for (int kc = 0; kc < 4; kc++) {
                int g = (kc * 4 + quad) ^ l16;
                short8 vb = *(short8*)&Vs[d * 128 + g * 8];
                cacc[nt] = __builtin_amdgcn_mfma_f32_16x16x32_bf16(pa[kc], vb, cacc[nt], 0, 0, 0);
            }
        }
    }

#pragma unroll
    for (int nt = 0; nt < 4; nt++)
#pragma unroll
        for (int reg = 0; reg < 4; reg++) {
            int q = q0 + w * 16 + quad * 4 + reg;
            ctxb[(size_t)q * D + h * DH + nt * 16 + l16] = f2b(cacc[nt][reg]);
        }
}

extern "C" void kernel_launch(void* const* d_in, const int* in_sizes, int n_in,
                              void* d_out, int out_size, void* d_ws, size_t ws_size,
                              hipStream_t stream)
{
    const float* X    = (const float*)d_in[0];
    const int*   mask = (const int*)d_in[1];
    const float* Wq   = (const float*)d_in[2];
    const float* bq   = (const float*)d_in[3];
    const float* Wk   = (const float*)d_in[4];
    const float* bk   = (const float*)d_in[5];
    const float* Wv   = (const float*)d_in[6];
    const float* bv   = (const float*)d_in[7];
    const float* Wo   = (const float*)d_in[8];
    const float* bo   = (const float*)d_in[9];

    float* out  = (float*)d_out;
    float* attn = out + (size_t)S * D;

    char* ws = (char*)d_ws;
    short* Xb   = (short*)ws;  ws += (size_t)S * D * 2;
    short* Wqb  = (short*)ws;  ws += (size_t)D * D * 2;
    short* Wkb  = (short*)ws;  ws += (size_t)D * D * 2;
    short* Wvb  = (short*)ws;  ws += (size_t)D * D * 2;
    short* Wob  = (short*)ws;  ws += (size_t)D * D * 2;
    short* Qb   = (short*)ws;  ws += (size_t)S * D * 2;
    short* Kb   = (short*)ws;  ws += (size_t)S * D * 2;
    short* Vt   = (short*)ws;  ws += (size_t)S * D * 2;
    short* ctxb = (short*)ws;  ws += (size_t)S * D * 2;
    unsigned long long* bits = (unsigned long long*)ws;

    dim3 blk(256);

    cvt_kernel<<<dim3((S * D) / 1024), blk, 0, stream>>>(X, Xb, S * D);
    cvt_kernel<<<dim3((D * D) / 1024), blk, 0, stream>>>(Wq, Wqb, D * D);
    cvt_kernel<<<dim3((D * D) / 1024), blk, 0, stream>>>(Wk, Wkb, D * D);
    cvt_kernel<<<dim3((D * D) / 1024), blk, 0, stream>>>(Wv, Wvb, D * D);
    cvt_kernel<<<dim3((D * D) / 1024), blk, 0, stream>>>(Wo, Wob, D * D);
    maskpack_kernel<<<dim3((S * S) / 256), blk, 0, stream>>>(mask, bits);

    gemm_mfma<<<dim3(D / 128, S / 128), blk, 0, stream>>>(Xb, Wqb, bq, Qb, nullptr, 1);
    gemm_mfma<<<dim3(D / 128, S / 128), blk, 0, stream>>>(Xb, Wkb, bk, Kb, nullptr, 0);
    gemm_mfma<<<dim3(D / 128, S / 128), blk, 0, stream>>>(Xb, Wvb, bv, Vt, nullptr, 2);

    attn_kernel<<<dim3(S / 64, H), blk, 0, stream>>>(Qb, Kb, Vt, bits, attn, ctxb);

    gemm_mfma<<<dim3(D / 128, S / 128), blk, 0, stream>>>(ctxb, Wob, bo, nullptr, out, 3);
}